// Round 14
// baseline (964.619 us; speedup 1.0000x reference)
//
#include <hip/hip_runtime.h>

#define B_ 64
#define S_ 2048
#define D_ 64
#define H_ 128
#define G_ 512
#define CH 16

typedef float f32x4 __attribute__((ext_vector_type(4)));
typedef _Float16 f16x8 __attribute__((ext_vector_type(8)));
typedef _Float16 f16x2 __attribute__((ext_vector_type(2)));

#define MFMA16H(a, b, c) __builtin_amdgcn_mfma_f32_16x16x32_f16((a), (b), (c), 0, 0, 0)
#define RCPF(x) __builtin_amdgcn_rcpf(x)
#define LOG2E 1.442695041f

#if __has_builtin(__builtin_amdgcn_exp2f)
#define EXP2(x) __builtin_amdgcn_exp2f(x)
#else
#define EXP2(x) exp2f(x)
#endif

// Per-step barrier: drain LDS, HW barrier, zero-cost compiler memory fence.
// (R7/R8/R13-proven; keeps global prefetch in flight, no scheduler pinning.)
#define STEP_SYNC() do {                                  \
    asm volatile("s_waitcnt lgkmcnt(0)" ::: "memory");    \
    __builtin_amdgcn_s_barrier();                         \
    asm volatile("" ::: "memory");                        \
} while (0)

__device__ __forceinline__ float sigm_f(float x) { return RCPF(1.0f + EXP2(x * -LOG2E)); }

// One block per batch element; 512 threads = 8 waves, 2/SIMD (R12 lesson).
// Wave w owns hidden units [16w,16w+16); all-gates-per-lane (R8); weights
// prescaled by -log2e (-2log2e for g) so gate chains feed exp2 directly (R9);
// xz hoisted to registers per chunk (R13). R14: f16 weights/h/x (more
// precise than bf16, and h-write is one v_cvt_f16_f32 instead of 4-op RNE
// bf16 round), and each gate's MFMA chain split 2x2-deep so the last
// accumulator lands ~50cy earlier.
__launch_bounds__(512, 1)
__global__ void lstm_fused(const float* __restrict__ x, const float* __restrict__ Wx,
                           const float* __restrict__ Wh, const float* __restrict__ bias,
                           const float* __restrict__ Wd, const float* __restrict__ bd,
                           float* __restrict__ out) {
    const int tid = threadIdx.x;
    const int lane = tid & 63;
    const int wid = tid >> 6;      // 0..7
    const int l15 = lane & 15;
    const int l4 = lane >> 4;      // 0..3
    const int bb = blockIdx.x;

    __shared__ alignas(16) _Float16 hist[CH][H_];  // h ring (f16), slot = t & 15
    __shared__ alignas(16) _Float16 xbf[CH][72];   // x chunk (f16, padded)
    __shared__ alignas(16) float xzc[CH][G_];      // [tm][unit*4+gate], prescaled

    ((unsigned*)hist)[tid] = 0u;     // f16 zero == 0x0000
    ((unsigned*)hist)[tid + 512] = 0u;

    const int col0 = wid * 16 + l15;               // hidden unit

    // --- prescaled Wh fragments (f16), col = gate*128+col0, k = kt*32+l4*8+e ---
    f16x8 bh[4][4];
#pragma unroll
    for (int ct = 0; ct < 4; ++ct) {
        const float msc = (ct == 2) ? (-2.0f * LOG2E) : (-LOG2E);
        const int col = ct * H_ + col0;
#pragma unroll
        for (int kt = 0; kt < 4; ++kt) {
            f16x8 v;
#pragma unroll
            for (int e = 0; e < 8; ++e)
                v[e] = (_Float16)(Wh[(kt * 32 + l4 * 8 + e) * G_ + col] * msc);
            bh[ct][kt] = v;
        }
    }
    // --- prescaled Wx fragments (f16) ---
    f16x8 bx[4][2];
#pragma unroll
    for (int ct = 0; ct < 4; ++ct) {
        const float msc = (ct == 2) ? (-2.0f * LOG2E) : (-LOG2E);
        const int col = ct * H_ + col0;
#pragma unroll
        for (int kt = 0; kt < 2; ++kt) {
            f16x8 v;
#pragma unroll
            for (int e = 0; e < 8; ++e)
                v[e] = (_Float16)(Wx[(kt * 32 + l4 * 8 + e) * G_ + col] * msc);
            bx[ct][kt] = v;
        }
    }

    float bvr[4];
#pragma unroll
    for (int ct = 0; ct < 4; ++ct)
        bvr[ct] = bias[ct * H_ + col0] * ((ct == 2) ? (-2.0f * LOG2E) : (-LOG2E));
    const float wd0 = Wd[lane * 2 + 0];
    const float wd1 = Wd[lane * 2 + 1];
    const float bdv = bd[0];
    float c_reg = 0.0f;

    const float* xb = x + (size_t)bb * S_ * D_;
    float* ob = out + (size_t)bb * S_;

    float xp0 = xb[tid * 2 + 0];
    float xp1 = xb[tid * 2 + 1];

    // persistent split acc chains (2 per gate): only reg 0 meaningful
    f32x4 p0a = {0.f, 0.f, 0.f, 0.f}, p0b = p0a, p1a = p0a, p1b = p0a;
    f32x4 p2a = p0a, p2b = p0a, p3a = p0a, p3b = p0a;

    for (int tc = 0; tc < S_; tc += CH) {
        // commit prefetched x chunk (data dep forces the vmcnt wait here)
        xbf[tid >> 5][(tid & 31) * 2 + 0] = (_Float16)xp0;
        xbf[tid >> 5][(tid & 31) * 2 + 1] = (_Float16)xp1;
        __syncthreads();
        if (tc + CH < S_) {
            xp0 = xb[(tc + CH) * D_ + tid * 2 + 0];
            xp1 = xb[(tc + CH) * D_ + tid * 2 + 1];
        }
        // xz_chunk = X[16x64] @ Wx + b (prescaled) -> [tm][unit*4+gate]
#pragma unroll
        for (int ct = 0; ct < 4; ++ct) {
            f32x4 cc = {bvr[ct], bvr[ct], bvr[ct], bvr[ct]};
#pragma unroll
            for (int kt = 0; kt < 2; ++kt) {
                const f16x8 a = *reinterpret_cast<const f16x8*>(&xbf[l15][kt * 32 + l4 * 8]);
                cc = MFMA16H(a, bx[ct][kt], cc);
            }
#pragma unroll
            for (int r = 0; r < 4; ++r)
                xzc[l4 * 4 + r][col0 * 4 + ct] = cc[r];   // D row = (lane>>4)*4+r [m89]
        }
        // dense head for the PREVIOUS chunk (hist = h_{tc-16..tc-1})
        if (tc > 0) {
#pragma unroll
            for (int s = 0; s < 2; ++s) {
                const int row = wid * 2 + s;
                const f16x2 hp = *reinterpret_cast<const f16x2*>(&hist[row][lane * 2]);
                float p = (float)hp[0] * wd0 + (float)hp[1] * wd1;
                p += __shfl_xor(p, 1);  p += __shfl_xor(p, 2);  p += __shfl_xor(p, 4);
                p += __shfl_xor(p, 8);  p += __shfl_xor(p, 16); p += __shfl_xor(p, 32);
                if (lane == 0) ob[tc - CH + row] = sigm_f(p + bdv);
            }
        }
        __syncthreads();   // xzc ready; hist fully consumed before overwrite

        // HOIST: this lane's xz for all 16 steps -> registers (R13-proven)
        f32x4 xzr[CH];
#pragma unroll
        for (int j = 0; j < CH; ++j)
            xzr[j] = *reinterpret_cast<const f32x4*>(&xzc[j][col0 * 4]);

#pragma unroll
        for (int tm = 0; tm < CH; ++tm) {
            const int prev = (tm + CH - 1) & (CH - 1);
            const _Float16* hsrc = hist[prev];
            const f16x8 a0 = *reinterpret_cast<const f16x8*>(&hsrc[ 0 + l4 * 8]);
            const f16x8 a1 = *reinterpret_cast<const f16x8*>(&hsrc[32 + l4 * 8]);
            const f16x8 a2 = *reinterpret_cast<const f16x8*>(&hsrc[64 + l4 * 8]);
            const f16x8 a3 = *reinterpret_cast<const f16x8*>(&hsrc[96 + l4 * 8]);

            // init reg 0 only; xz in the a-chain, 0 in the b-chain
            p0a[0] = xzr[tm][0];  p1a[0] = xzr[tm][1];
            p2a[0] = xzr[tm][2];  p3a[0] = xzr[tm][3];
            p0b[0] = 0.f;  p1b[0] = 0.f;  p2b[0] = 0.f;  p3b[0] = 0.f;

            // 2x2-deep split chains per gate (last result ~50cy earlier)
            p0a = MFMA16H(a0, bh[0][0], p0a);  p0b = MFMA16H(a2, bh[0][2], p0b);
            p1a = MFMA16H(a0, bh[1][0], p1a);  p1b = MFMA16H(a2, bh[1][2], p1b);
            p2a = MFMA16H(a0, bh[2][0], p2a);  p2b = MFMA16H(a2, bh[2][2], p2b);
            p3a = MFMA16H(a0, bh[3][0], p3a);  p3b = MFMA16H(a2, bh[3][2], p3b);
            p0a = MFMA16H(a1, bh[0][1], p0a);  p0b = MFMA16H(a3, bh[0][3], p0b);
            p1a = MFMA16H(a1, bh[1][1], p1a);  p1b = MFMA16H(a3, bh[1][3], p1b);
            p2a = MFMA16H(a1, bh[2][1], p2a);  p2b = MFMA16H(a3, bh[2][3], p2b);
            p3a = MFMA16H(a1, bh[3][1], p3a);  p3b = MFMA16H(a3, bh[3][3], p3b);

            // gates (prescaled z feeds exp2 directly)
            const float zi = p0a[0] + p0b[0];
            const float zf = p1a[0] + p1b[0];
            const float zg = p2a[0] + p2b[0];
            const float zo = p3a[0] + p3b[0];
            const float iv = RCPF(1.0f + EXP2(zi));
            const float fv = RCPF(1.0f + EXP2(zf));
            const float gv = __builtin_fmaf(2.0f, RCPF(1.0f + EXP2(zg)), -1.0f);
            const float ov = RCPF(1.0f + EXP2(zo));

            c_reg = __builtin_fmaf(fv, c_reg, iv * gv);
            const float th = __builtin_fmaf(
                2.0f, RCPF(1.0f + EXP2(c_reg * (-2.0f * LOG2E))), -1.0f);
            const float hv = ov * th;

            if (lane < 16) hist[tm][col0] = (_Float16)hv;   // 1-instr cvt
            STEP_SYNC();   // h_t visible to all waves for step t+1
        }
    }

    // dense head for the final 16 steps
#pragma unroll
    for (int s = 0; s < 2; ++s) {
        const int row = wid * 2 + s;
        const f16x2 hp = *reinterpret_cast<const f16x2*>(&hist[row][lane * 2]);
        float p = (float)hp[0] * wd0 + (float)hp[1] * wd1;
        p += __shfl_xor(p, 1);  p += __shfl_xor(p, 2);  p += __shfl_xor(p, 4);
        p += __shfl_xor(p, 8);  p += __shfl_xor(p, 16); p += __shfl_xor(p, 32);
        if (lane == 0) ob[S_ - CH + row] = sigm_f(p + bdv);
    }
}

extern "C" void kernel_launch(void* const* d_in, const int* in_sizes, int n_in,
                              void* d_out, int out_size, void* d_ws, size_t ws_size,
                              hipStream_t stream) {
    const float* x  = (const float*)d_in[0];
    const float* Wx = (const float*)d_in[1];
    const float* Wh = (const float*)d_in[2];
    const float* b  = (const float*)d_in[3];
    const float* Wd = (const float*)d_in[4];
    const float* bd = (const float*)d_in[5];
    float* out = (float*)d_out;

    lstm_fused<<<B_, 512, 0, stream>>>(x, Wx, Wh, b, Wd, bd, out);
}

// Round 15
// 891.562 us; speedup vs baseline: 1.0819x; 1.0819x over previous
//
#include <hip/hip_runtime.h>

#define B_ 64
#define S_ 2048
#define D_ 64
#define H_ 128
#define G_ 512
#define CH 16

typedef float f32x4 __attribute__((ext_vector_type(4)));
typedef short bf16x8 __attribute__((ext_vector_type(8)));

#define MFMA16(a, b, c) __builtin_amdgcn_mfma_f32_16x16x32_bf16((a), (b), (c), 0, 0, 0)
#define RCPF(x) __builtin_amdgcn_rcpf(x)
#define LOG2E 1.442695041f

#if __has_builtin(__builtin_amdgcn_exp2f)
#define EXP2(x) __builtin_amdgcn_exp2f(x)
#else
#define EXP2(x) exp2f(x)
#endif

// Per-step barrier: drain LDS, HW barrier, zero-cost compiler memory fence.
// (R7/R8/R13-proven; keeps global prefetch in flight, no scheduler pinning.)
#define STEP_SYNC() do {                                  \
    asm volatile("s_waitcnt lgkmcnt(0)" ::: "memory");    \
    __builtin_amdgcn_s_barrier();                         \
    asm volatile("" ::: "memory");                        \
} while (0)

__device__ __forceinline__ short f2bf(float f) {
    unsigned u = __builtin_bit_cast(unsigned, f);
    return (short)((u + 0x7FFFu + ((u >> 16) & 1u)) >> 16);  // RNE
}
__device__ __forceinline__ float bflo(unsigned u) { return __builtin_bit_cast(float, u << 16); }
__device__ __forceinline__ float bfhi(unsigned u) { return __builtin_bit_cast(float, u & 0xFFFF0000u); }
__device__ __forceinline__ float sigm_f(float x) { return RCPF(1.0f + EXP2(x * -LOG2E)); }

// One block per batch element; 512 threads = 8 waves, 2/SIMD (R12 lesson:
// the co-resident wave hides the serial tail). Wave w owns hidden units
// [16w,16w+16); all-gates-per-lane (R8); weights prescaled by -log2e
// (-2log2e for g) so gate chains feed exp2 directly (R9); xz hoisted to
// registers per chunk (R13). R15: two fma-folds shorten the dependent gate
// spine — i*g = fma(2i, r_g, -i) and h = fma(2o, r_th, -o) (the 2x/neg muls
// run parallel to the rcp). bf16 MFMA kept (R14: f16 MFMA is ~6% slower, m64).
__launch_bounds__(512, 1)
__global__ void lstm_fused(const float* __restrict__ x, const float* __restrict__ Wx,
                           const float* __restrict__ Wh, const float* __restrict__ bias,
                           const float* __restrict__ Wd, const float* __restrict__ bd,
                           float* __restrict__ out) {
    const int tid = threadIdx.x;
    const int lane = tid & 63;
    const int wid = tid >> 6;      // 0..7
    const int l15 = lane & 15;
    const int l4 = lane >> 4;      // 0..3
    const int bb = blockIdx.x;

    __shared__ alignas(16) short hist[CH][H_];   // h ring (bf16), slot = t & 15
    __shared__ alignas(16) short xbf[CH][72];    // x chunk (padded)
    __shared__ alignas(16) float xzc[CH][G_];    // [tm][unit*4+gate], prescaled

    ((unsigned*)hist)[tid] = 0u;
    ((unsigned*)hist)[tid + 512] = 0u;

    const int col0 = wid * 16 + l15;             // hidden unit

    // --- prescaled Wh B-fragments, col = gate*128 + col0, k = kt*32+l4*8+e ---
    bf16x8 bh[4][4];
#pragma unroll
    for (int ct = 0; ct < 4; ++ct) {
        const float msc = (ct == 2) ? (-2.0f * LOG2E) : (-LOG2E);
        const int col = ct * H_ + col0;
#pragma unroll
        for (int kt = 0; kt < 4; ++kt) {
            bf16x8 v;
#pragma unroll
            for (int e = 0; e < 8; ++e)
                v[e] = f2bf(Wh[(kt * 32 + l4 * 8 + e) * G_ + col] * msc);
            bh[ct][kt] = v;
        }
    }
    // --- prescaled Wx B-fragments ---
    bf16x8 bx[4][2];
#pragma unroll
    for (int ct = 0; ct < 4; ++ct) {
        const float msc = (ct == 2) ? (-2.0f * LOG2E) : (-LOG2E);
        const int col = ct * H_ + col0;
#pragma unroll
        for (int kt = 0; kt < 2; ++kt) {
            bf16x8 v;
#pragma unroll
            for (int e = 0; e < 8; ++e)
                v[e] = f2bf(Wx[(kt * 32 + l4 * 8 + e) * G_ + col] * msc);
            bx[ct][kt] = v;
        }
    }

    float bvr[4];
#pragma unroll
    for (int ct = 0; ct < 4; ++ct)
        bvr[ct] = bias[ct * H_ + col0] * ((ct == 2) ? (-2.0f * LOG2E) : (-LOG2E));
    const float wd0 = Wd[lane * 2 + 0];
    const float wd1 = Wd[lane * 2 + 1];
    const float bdv = bd[0];
    float c_reg = 0.0f;

    const float* xb = x + (size_t)bb * S_ * D_;
    float* ob = out + (size_t)bb * S_;

    float xp0 = xb[tid * 2 + 0];
    float xp1 = xb[tid * 2 + 1];

    // persistent acc chains: only reg 0 meaningful (rows 1-3 stale, bounded)
    f32x4 acc0 = {0.f, 0.f, 0.f, 0.f}, acc1 = acc0, acc2 = acc0, acc3 = acc0;

    for (int tc = 0; tc < S_; tc += CH) {
        // commit prefetched x chunk (data dep forces the vmcnt wait here)
        xbf[tid >> 5][(tid & 31) * 2 + 0] = f2bf(xp0);
        xbf[tid >> 5][(tid & 31) * 2 + 1] = f2bf(xp1);
        __syncthreads();
        if (tc + CH < S_) {
            xp0 = xb[(tc + CH) * D_ + tid * 2 + 0];
            xp1 = xb[(tc + CH) * D_ + tid * 2 + 1];
        }
        // xz_chunk = X[16x64] @ Wx + b (prescaled) -> [tm][unit*4+gate]
#pragma unroll
        for (int ct = 0; ct < 4; ++ct) {
            f32x4 cc = {bvr[ct], bvr[ct], bvr[ct], bvr[ct]};
#pragma unroll
            for (int kt = 0; kt < 2; ++kt) {
                const bf16x8 a = *reinterpret_cast<const bf16x8*>(&xbf[l15][kt * 32 + l4 * 8]);
                cc = MFMA16(a, bx[ct][kt], cc);
            }
#pragma unroll
            for (int r = 0; r < 4; ++r)
                xzc[l4 * 4 + r][col0 * 4 + ct] = cc[r];   // D row = (lane>>4)*4+r [m89]
        }
        // dense head for the PREVIOUS chunk (hist = h_{tc-16..tc-1})
        if (tc > 0) {
#pragma unroll
            for (int s = 0; s < 2; ++s) {
                const int row = wid * 2 + s;
                const unsigned hp = *reinterpret_cast<const unsigned*>(&hist[row][lane * 2]);
                float p = bflo(hp) * wd0 + bfhi(hp) * wd1;
                p += __shfl_xor(p, 1);  p += __shfl_xor(p, 2);  p += __shfl_xor(p, 4);
                p += __shfl_xor(p, 8);  p += __shfl_xor(p, 16); p += __shfl_xor(p, 32);
                if (lane == 0) ob[tc - CH + row] = sigm_f(p + bdv);
            }
        }
        __syncthreads();   // xzc ready; hist fully consumed before overwrite

        // HOIST: this lane's xz for all 16 steps -> registers (R13-proven)
        f32x4 xzr[CH];
#pragma unroll
        for (int j = 0; j < CH; ++j)
            xzr[j] = *reinterpret_cast<const f32x4*>(&xzc[j][col0 * 4]);

#pragma unroll
        for (int tm = 0; tm < CH; ++tm) {
            const int prev = (tm + CH - 1) & (CH - 1);
            const short* hsrc = hist[prev];
            const bf16x8 a0 = *reinterpret_cast<const bf16x8*>(&hsrc[ 0 + l4 * 8]);
            const bf16x8 a1 = *reinterpret_cast<const bf16x8*>(&hsrc[32 + l4 * 8]);
            const bf16x8 a2 = *reinterpret_cast<const bf16x8*>(&hsrc[64 + l4 * 8]);
            const bf16x8 a3 = *reinterpret_cast<const bf16x8*>(&hsrc[96 + l4 * 8]);

            // init only reg 0 of each chain (row l4*4 is the only row read)
            acc0[0] = xzr[tm][0];  acc1[0] = xzr[tm][1];
            acc2[0] = xzr[tm][2];  acc3[0] = xzr[tm][3];

            acc0 = MFMA16(a0, bh[0][0], acc0);
            acc1 = MFMA16(a0, bh[1][0], acc1);
            acc2 = MFMA16(a0, bh[2][0], acc2);
            acc3 = MFMA16(a0, bh[3][0], acc3);
            acc0 = MFMA16(a1, bh[0][1], acc0);
            acc1 = MFMA16(a1, bh[1][1], acc1);
            acc2 = MFMA16(a1, bh[2][1], acc2);
            acc3 = MFMA16(a1, bh[3][1], acc3);
            acc0 = MFMA16(a2, bh[0][2], acc0);
            acc1 = MFMA16(a2, bh[1][2], acc1);
            acc2 = MFMA16(a2, bh[2][2], acc2);
            acc3 = MFMA16(a2, bh[3][2], acc3);
            acc0 = MFMA16(a3, bh[0][3], acc0);
            acc1 = MFMA16(a3, bh[1][3], acc1);
            acc2 = MFMA16(a3, bh[2][3], acc2);
            acc3 = MFMA16(a3, bh[3][3], acc3);

            // gates (prescaled z feeds exp2 directly); fma-folded spine:
            // i*g = fma(2i, r_g, -i)   [g = 2*r_g - 1]
            // h   = fma(2o, r_th, -o)  [th = 2*r_th - 1]
            const float iv  = RCPF(1.0f + EXP2(acc0[0]));
            const float fv  = RCPF(1.0f + EXP2(acc1[0]));
            const float rg  = RCPF(1.0f + EXP2(acc2[0]));
            const float ov  = RCPF(1.0f + EXP2(acc3[0]));
            const float ivg = __builtin_fmaf(2.0f * iv, rg, -iv);

            c_reg = __builtin_fmaf(fv, c_reg, ivg);
            const float rth = RCPF(1.0f + EXP2(c_reg * (-2.0f * LOG2E)));
            const float hv  = __builtin_fmaf(2.0f * ov, rth, -ov);

            if (lane < 16) hist[tm][col0] = f2bf(hv);
            STEP_SYNC();   // h_t visible to all waves for step t+1
        }
    }

    // dense head for the final 16 steps
#pragma unroll
    for (int s = 0; s < 2; ++s) {
        const int row = wid * 2 + s;
        const unsigned hp = *reinterpret_cast<const unsigned*>(&hist[row][lane * 2]);
        float p = bflo(hp) * wd0 + bfhi(hp) * wd1;
        p += __shfl_xor(p, 1);  p += __shfl_xor(p, 2);  p += __shfl_xor(p, 4);
        p += __shfl_xor(p, 8);  p += __shfl_xor(p, 16); p += __shfl_xor(p, 32);
        if (lane == 0) ob[S_ - CH + row] = sigm_f(p + bdv);
    }
}

extern "C" void kernel_launch(void* const* d_in, const int* in_sizes, int n_in,
                              void* d_out, int out_size, void* d_ws, size_t ws_size,
                              hipStream_t stream) {
    const float* x  = (const float*)d_in[0];
    const float* Wx = (const float*)d_in[1];
    const float* Wh = (const float*)d_in[2];
    const float* b  = (const float*)d_in[3];
    const float* Wd = (const float*)d_in[4];
    const float* bd = (const float*)d_in[5];
    float* out = (float*)d_out;

    lstm_fused<<<B_, 512, 0, stream>>>(x, Wx, Wh, b, Wd, bd, out);
}